// Round 2
// baseline (1253.377 us; speedup 1.0000x reference)
//
#include <hip/hip_runtime.h>

#define N_NODES 50000
#define N_EDGES 800000
#define N_B 2
#define N_C 64
#define BN_ROWS (N_B * N_NODES)

// ---------------- degree count (non-self-loop edges per source row) ----------
__global__ __launch_bounds__(256) void k_deg(const int* __restrict__ ei, int* __restrict__ deg) {
  int e = blockIdx.x * 256 + threadIdx.x;
  if (e >= N_EDGES) return;
  int r = ei[e];
  int c = ei[N_EDGES + e];
  if (r != c) atomicAdd(&deg[r], 1);
}

// ---------------- exclusive scan of deg -> rowptr, cursor; dis = deg^-1/2 ----
__global__ __launch_bounds__(1024) void k_scan(const int* __restrict__ deg, int* __restrict__ rowptr,
                                               int* __restrict__ cursor, float* __restrict__ dis) {
  __shared__ int sa[1024];
  __shared__ int sb[1024];
  int t = threadIdx.x;
  const int CH = (N_NODES + 1023) / 1024;  // 49
  int lo = t * CH; if (lo > N_NODES) lo = N_NODES;
  int hi = lo + CH; if (hi > N_NODES) hi = N_NODES;
  int s = 0;
  for (int i = lo; i < hi; ++i) s += deg[i];
  sa[t] = s;
  __syncthreads();
  int* src = sa; int* dst = sb;
  for (int off = 1; off < 1024; off <<= 1) {
    int v = src[t];
    if (t >= off) v += src[t - off];
    dst[t] = v;
    __syncthreads();
    int* tmp = src; src = dst; dst = tmp;
  }
  int run = src[t] - s;  // exclusive prefix
  for (int i = lo; i < hi; ++i) {
    int d = deg[i];
    rowptr[i] = run;
    cursor[i] = run;
    dis[i] = d > 0 ? rsqrtf((float)d) : 0.0f;
    run += d;
  }
  if (t == 1023) rowptr[N_NODES] = src[1023];
}

// ---------------- fill CSR (col + lap value), skipping self loops ------------
__global__ __launch_bounds__(256) void k_fill(const int* __restrict__ ei, const float* __restrict__ ew,
                                              const float* __restrict__ dis, int* __restrict__ cursor,
                                              int* __restrict__ ccol, float* __restrict__ cval) {
  int e = blockIdx.x * 256 + threadIdx.x;
  if (e >= N_EDGES) return;
  int r = ei[e];
  int c = ei[N_EDGES + e];
  if (r == c) return;
  float v = -dis[r] * ew[e] * dis[c];
  int pos = atomicAdd(&cursor[r], 1);
  ccol[pos] = c;
  cval[pos] = v;
}

// ---------------- SPMM: dst[b,n,:] = sum_e lap_e * src[b,col_e,:] ------------
// one wave64 per (b,n) row; lane = channel -> coalesced 256B gather per edge
__global__ __launch_bounds__(256) void k_spmm(const float* __restrict__ src, float* __restrict__ dst,
                                              const int* __restrict__ rowptr, const int* __restrict__ ccol,
                                              const float* __restrict__ cval) {
  int wid = (blockIdx.x * 256 + threadIdx.x) >> 6;
  int lane = threadIdx.x & 63;
  if (wid >= BN_ROWS) return;
  int n = wid % N_NODES;
  int b = wid / N_NODES;
  const float* s = src + (size_t)b * N_NODES * N_C;
  int i = rowptr[n];
  int end = rowptr[n + 1];
  float acc = 0.0f;
  // 2-edge unroll for two independent load chains
  for (; i + 1 < end; i += 2) {
    int c0 = ccol[i];
    int c1 = ccol[i + 1];
    float v0 = cval[i];
    float v1 = cval[i + 1];
    float x0 = s[(size_t)c0 * N_C + lane];
    float x1 = s[(size_t)c1 * N_C + lane];
    acc += v0 * x0;
    acc += v1 * x1;
  }
  if (i < end) acc += cval[i] * s[(size_t)ccol[i] * N_C + lane];
  dst[(size_t)wid * N_C + lane] = acc;
}

// ---------------- fused GEMM: out = x@(W0-W2) + Tx1@W1 + Z@(2*W2) + bias -----
// Z is read from `out` itself (spmm2 wrote it there); each block reads only the
// rows it later writes, and all reads precede the stores -> safe in-place.
__global__ __launch_bounds__(256) void k_gemm(const float* __restrict__ x, const float* __restrict__ tx1,
                                              const float* __restrict__ w, const float* __restrict__ bias,
                                              float* __restrict__ out) {
  __shared__ float wl[3 * 64 * 64];  // 48KB combined weights
  int t = threadIdx.x;
  for (int i = t; i < 4096; i += 256) {
    float w0 = w[i];
    float w1 = w[4096 + i];
    float w2 = w[8192 + i];
    wl[i] = w0 - w2;
    wl[4096 + i] = w1;
    wl[8192 + i] = 2.0f * w2;
  }
  __syncthreads();
  int tx = t & 15;       // col group: cols 4*tx .. 4*tx+3
  int ty = t >> 4;       // row group: rows row0 .. row0+3
  long row0 = (long)blockIdx.x * 64 + (long)ty * 4;
  const float* A[3] = {x, tx1, out};
  float4 acc[4];
  float4 bv = *(const float4*)&bias[tx * 4];
#pragma unroll
  for (int i = 0; i < 4; ++i) acc[i] = bv;
  bool valid[4];
#pragma unroll
  for (int i = 0; i < 4; ++i) valid[i] = (row0 + i) < BN_ROWS;

  for (int ch = 0; ch < 3; ++ch) {
    const float* Ab = A[ch];
    const float* Wb = &wl[ch * 4096];
    for (int k4 = 0; k4 < 64; k4 += 4) {
      float4 a[4];
#pragma unroll
      for (int i = 0; i < 4; ++i) {
        if (valid[i]) {
          a[i] = *(const float4*)&Ab[(row0 + i) * 64 + k4];
        } else {
          a[i] = make_float4(0.f, 0.f, 0.f, 0.f);
        }
      }
#pragma unroll
      for (int kk = 0; kk < 4; ++kk) {
        float4 wv = *(const float4*)&Wb[(k4 + kk) * 64 + tx * 4];
#pragma unroll
        for (int i = 0; i < 4; ++i) {
          float av = (kk == 0) ? a[i].x : (kk == 1) ? a[i].y : (kk == 2) ? a[i].z : a[i].w;
          acc[i].x += av * wv.x;
          acc[i].y += av * wv.y;
          acc[i].z += av * wv.z;
          acc[i].w += av * wv.w;
        }
      }
    }
  }
#pragma unroll
  for (int i = 0; i < 4; ++i) {
    if (valid[i]) *(float4*)&out[(row0 + i) * 64 + tx * 4] = acc[i];
  }
}

extern "C" void kernel_launch(void* const* d_in, const int* in_sizes, int n_in,
                              void* d_out, int out_size, void* d_ws, size_t ws_size,
                              hipStream_t stream) {
  const float* x = (const float*)d_in[0];
  const int* ei = (const int*)d_in[1];        // [2, E] int32
  const float* ew = (const float*)d_in[2];
  const float* w = (const float*)d_in[3];     // [3,64,64]
  const float* bias = (const float*)d_in[4];  // [64]
  float* out = (float*)d_out;

  // workspace layout (4-byte units, 256B-aligned chunks)
  int* ws32 = (int*)d_ws;
  const size_t NA = 50048;  // padded N
  int* deg = ws32;
  int* cursor = deg + NA;
  float* dis = (float*)(cursor + NA);
  int* rowptr = (int*)(dis + NA);          // N+1 used
  int* ccol = rowptr + NA;
  float* cval = (float*)(ccol + N_EDGES);
  float* tx1 = cval + N_EDGES;             // BN_ROWS*64 floats
  const size_t NEED = ((size_t)(4 * NA + 2 * N_EDGES) + (size_t)BN_ROWS * N_C) * 4;
  if (ws_size < NEED) return;  // clean fail instead of corruption

  hipMemsetAsync(deg, 0, N_NODES * sizeof(int), stream);
  k_deg<<<(N_EDGES + 255) / 256, 256, 0, stream>>>(ei, deg);
  k_scan<<<1, 1024, 0, stream>>>(deg, rowptr, cursor, dis);
  k_fill<<<(N_EDGES + 255) / 256, 256, 0, stream>>>(ei, ew, dis, cursor, ccol, cval);
  // Tx1 = L x
  k_spmm<<<(BN_ROWS * N_C) / 256, 256, 0, stream>>>(x, tx1, rowptr, ccol, cval);
  // Z = L Tx1  (into d_out)
  k_spmm<<<(BN_ROWS * N_C) / 256, 256, 0, stream>>>(tx1, out, rowptr, ccol, cval);
  // out = x@(W0-W2) + Tx1@W1 + Z@(2W2) + bias  (in-place over Z)
  k_gemm<<<(BN_ROWS + 63) / 64, 256, 0, stream>>>(x, tx1, w, bias, out);
}

// Round 3
// 531.511 us; speedup vs baseline: 2.3581x; 2.3581x over previous
//
#include <hip/hip_runtime.h>

#define N_NODES 50000
#define N_EDGES 800000
#define N_B 2
#define N_C 64
#define BN_ROWS (N_B * N_NODES)

// ---------------- degree count (non-self-loop edges per source row) ----------
__global__ __launch_bounds__(256) void k_deg(const int* __restrict__ ei, int* __restrict__ deg) {
  int e = blockIdx.x * 256 + threadIdx.x;
  if (e >= N_EDGES) return;
  int r = ei[e];
  int c = ei[N_EDGES + e];
  if (r != c) atomicAdd(&deg[r], 1);
}

// ---------------- exclusive scan of deg -> rowptr, cursor; dis = deg^-1/2 ----
__global__ __launch_bounds__(1024) void k_scan(const int* __restrict__ deg, int* __restrict__ rowptr,
                                               int* __restrict__ cursor, float* __restrict__ dis) {
  __shared__ int sa[1024];
  __shared__ int sb[1024];
  int t = threadIdx.x;
  const int CH = (N_NODES + 1023) / 1024;  // 49
  int lo = t * CH; if (lo > N_NODES) lo = N_NODES;
  int hi = lo + CH; if (hi > N_NODES) hi = N_NODES;
  int s = 0;
  for (int i = lo; i < hi; ++i) s += deg[i];
  sa[t] = s;
  __syncthreads();
  int* src = sa; int* dst = sb;
  for (int off = 1; off < 1024; off <<= 1) {
    int v = src[t];
    if (t >= off) v += src[t - off];
    dst[t] = v;
    __syncthreads();
    int* tmp = src; src = dst; dst = tmp;
  }
  int run = src[t] - s;  // exclusive prefix
  for (int i = lo; i < hi; ++i) {
    int d = deg[i];
    rowptr[i] = run;
    cursor[i] = run;
    dis[i] = d > 0 ? rsqrtf((float)d) : 0.0f;
    run += d;
  }
  if (t == 1023) rowptr[N_NODES] = src[1023];
}

// ---------------- fill CSR (col + lap value), skipping self loops ------------
__global__ __launch_bounds__(256) void k_fill(const int* __restrict__ ei, const float* __restrict__ ew,
                                              const float* __restrict__ dis, int* __restrict__ cursor,
                                              int* __restrict__ ccol, float* __restrict__ cval) {
  int e = blockIdx.x * 256 + threadIdx.x;
  if (e >= N_EDGES) return;
  int r = ei[e];
  int c = ei[N_EDGES + e];
  if (r == c) return;
  float v = -dis[r] * ew[e] * dis[c];
  int pos = atomicAdd(&cursor[r], 1);
  ccol[pos] = c;
  cval[pos] = v;
}

// ---------------- SPMM: dst[b,n,:] = sum_e lap_e * src[b,col_e,:] ------------
// one wave64 per (b,n) row; lane = channel -> coalesced 256B gather per edge
__global__ __launch_bounds__(256) void k_spmm(const float* __restrict__ src, float* __restrict__ dst,
                                              const int* __restrict__ rowptr, const int* __restrict__ ccol,
                                              const float* __restrict__ cval) {
  int wid = (blockIdx.x * 256 + threadIdx.x) >> 6;
  int lane = threadIdx.x & 63;
  if (wid >= BN_ROWS) return;
  int n = wid % N_NODES;
  int b = wid / N_NODES;
  const float* s = src + (size_t)b * N_NODES * N_C;
  int i = rowptr[n];
  int end = rowptr[n + 1];
  float acc = 0.0f;
  // 2-edge unroll for two independent load chains
  for (; i + 1 < end; i += 2) {
    int c0 = ccol[i];
    int c1 = ccol[i + 1];
    float v0 = cval[i];
    float v1 = cval[i + 1];
    float x0 = s[(size_t)c0 * N_C + lane];
    float x1 = s[(size_t)c1 * N_C + lane];
    acc += v0 * x0;
    acc += v1 * x1;
  }
  if (i < end) acc += cval[i] * s[(size_t)ccol[i] * N_C + lane];
  dst[(size_t)wid * N_C + lane] = acc;
}

// ---------------- fused GEMM: out = x@(W0-W2) + Tx1@W1 + Z@(2*W2) + bias -----
// Z is read from `out` itself (spmm2 wrote it there); each block reads only the
// rows it later writes, and all reads precede the stores -> safe in-place.
// Named accumulators + capped unroll => no scratch spill (round-2 lesson:
// full unroll + runtime-indexed pointer array spilled 2.8KB/thread = 1.1GB).
#define FMA4(ACC, AV, WV) \
  ACC.x += (AV) * (WV).x; ACC.y += (AV) * (WV).y; ACC.z += (AV) * (WV).z; ACC.w += (AV) * (WV).w;

#define CH_STEP(Wb, KK, A0, A1, A2, A3) { \
  const float4 wv0 = *(const float4*)&(Wb)[(k4 + (KK)) * 64 + tx8]; \
  const float4 wv1 = *(const float4*)&(Wb)[(k4 + (KK)) * 64 + tx8 + 4]; \
  FMA4(acc00, A0, wv0) FMA4(acc01, A0, wv1) \
  FMA4(acc10, A1, wv0) FMA4(acc11, A1, wv1) \
  FMA4(acc20, A2, wv0) FMA4(acc21, A2, wv1) \
  FMA4(acc30, A3, wv0) FMA4(acc31, A3, wv1) }

#define CH_PASS(Ab, Wb) \
  _Pragma("unroll 2") \
  for (int k4 = 0; k4 < 64; k4 += 4) { \
    const float4 a0 = *(const float4*)&(Ab)[r0 * 64 + (size_t)k4]; \
    const float4 a1 = *(const float4*)&(Ab)[r1 * 64 + (size_t)k4]; \
    const float4 a2 = *(const float4*)&(Ab)[r2 * 64 + (size_t)k4]; \
    const float4 a3 = *(const float4*)&(Ab)[r3 * 64 + (size_t)k4]; \
    CH_STEP(Wb, 0, a0.x, a1.x, a2.x, a3.x) \
    CH_STEP(Wb, 1, a0.y, a1.y, a2.y, a3.y) \
    CH_STEP(Wb, 2, a0.z, a1.z, a2.z, a3.z) \
    CH_STEP(Wb, 3, a0.w, a1.w, a2.w, a3.w) \
  }

__global__ __launch_bounds__(256) void k_gemm(const float* __restrict__ x,
                                              const float* __restrict__ tx1,
                                              const float* __restrict__ w,
                                              const float* __restrict__ bias,
                                              float* out) {
  __shared__ float wl[3 * 4096];  // 48KB combined weights -> 3 blocks/CU
  int t = threadIdx.x;
  for (int i = t; i < 4096; i += 256) {
    float w0 = w[i];
    float w1 = w[4096 + i];
    float w2 = w[8192 + i];
    wl[i] = w0 - w2;
    wl[4096 + i] = w1;
    wl[8192 + i] = 2.0f * w2;
  }
  __syncthreads();
  const int tx8 = (t & 7) * 8;        // cols tx8 .. tx8+7
  const int rg = t >> 3;              // 0..31 -> 4 rows each; tile = 128 rows
  const size_t base = (size_t)blockIdx.x * 128 + (size_t)rg * 4;
  const size_t rmax = BN_ROWS - 1;
  const size_t r0 = base + 0 < rmax ? base + 0 : rmax;
  const size_t r1 = base + 1 < rmax ? base + 1 : rmax;
  const size_t r2 = base + 2 < rmax ? base + 2 : rmax;
  const size_t r3 = base + 3 < rmax ? base + 3 : rmax;
  const float4 bv0 = *(const float4*)&bias[tx8];
  const float4 bv1 = *(const float4*)&bias[tx8 + 4];
  float4 acc00 = bv0, acc01 = bv1;
  float4 acc10 = bv0, acc11 = bv1;
  float4 acc20 = bv0, acc21 = bv1;
  float4 acc30 = bv0, acc31 = bv1;

  CH_PASS(x, wl)
  CH_PASS(tx1, (wl + 4096))
  CH_PASS(out, (wl + 8192))

  if (base + 0 < BN_ROWS) { *(float4*)&out[(base + 0) * 64 + tx8] = acc00; *(float4*)&out[(base + 0) * 64 + tx8 + 4] = acc01; }
  if (base + 1 < BN_ROWS) { *(float4*)&out[(base + 1) * 64 + tx8] = acc10; *(float4*)&out[(base + 1) * 64 + tx8 + 4] = acc11; }
  if (base + 2 < BN_ROWS) { *(float4*)&out[(base + 2) * 64 + tx8] = acc20; *(float4*)&out[(base + 2) * 64 + tx8 + 4] = acc21; }
  if (base + 3 < BN_ROWS) { *(float4*)&out[(base + 3) * 64 + tx8] = acc30; *(float4*)&out[(base + 3) * 64 + tx8 + 4] = acc31; }
}

extern "C" void kernel_launch(void* const* d_in, const int* in_sizes, int n_in,
                              void* d_out, int out_size, void* d_ws, size_t ws_size,
                              hipStream_t stream) {
  const float* x = (const float*)d_in[0];
  const int* ei = (const int*)d_in[1];        // [2, E] int32
  const float* ew = (const float*)d_in[2];
  const float* w = (const float*)d_in[3];     // [3,64,64]
  const float* bias = (const float*)d_in[4];  // [64]
  float* out = (float*)d_out;

  // workspace layout (4-byte units, 256B-aligned chunks)
  int* ws32 = (int*)d_ws;
  const size_t NA = 50048;  // padded N
  int* deg = ws32;
  int* cursor = deg + NA;
  float* dis = (float*)(cursor + NA);
  int* rowptr = (int*)(dis + NA);          // N+1 used
  int* ccol = rowptr + NA;
  float* cval = (float*)(ccol + N_EDGES);
  float* tx1 = cval + N_EDGES;             // BN_ROWS*64 floats
  const size_t NEED = ((size_t)(4 * NA + 2 * N_EDGES) + (size_t)BN_ROWS * N_C) * 4;
  if (ws_size < NEED) return;  // clean fail instead of corruption

  hipMemsetAsync(deg, 0, N_NODES * sizeof(int), stream);
  k_deg<<<(N_EDGES + 255) / 256, 256, 0, stream>>>(ei, deg);
  k_scan<<<1, 1024, 0, stream>>>(deg, rowptr, cursor, dis);
  k_fill<<<(N_EDGES + 255) / 256, 256, 0, stream>>>(ei, ew, dis, cursor, ccol, cval);
  // Tx1 = L x
  k_spmm<<<(BN_ROWS * N_C) / 256, 256, 0, stream>>>(x, tx1, rowptr, ccol, cval);
  // Z = L Tx1  (into d_out)
  k_spmm<<<(BN_ROWS * N_C) / 256, 256, 0, stream>>>(tx1, out, rowptr, ccol, cval);
  // out = x@(W0-W2) + Tx1@W1 + Z@(2W2) + bias  (in-place over Z)
  k_gemm<<<(BN_ROWS + 127) / 128, 256, 0, stream>>>(x, tx1, w, bias, out);
}

// Round 4
// 370.235 us; speedup vs baseline: 3.3854x; 1.4356x over previous
//
#include <hip/hip_runtime.h>

#define N_NODES 50000
#define N_EDGES 800000
#define N_B 2
#define N_C 64
#define BN_ROWS (N_B * N_NODES)

// ---------------- degree count (non-self-loop edges per source row) ----------
__global__ __launch_bounds__(256) void k_deg(const int* __restrict__ ei, int* __restrict__ deg) {
  int e = blockIdx.x * 256 + threadIdx.x;
  if (e >= N_EDGES) return;
  int r = ei[e];
  int c = ei[N_EDGES + e];
  if (r != c) atomicAdd(&deg[r], 1);
}

// ---------------- segment allocator: per-wave prefix + 1 atomic per wave -----
// Replaces the 1-block scan (133us, 0.13% occupancy). Row segments need only
// be DISJOINT, not in row order -> allocate via global counter.
__global__ __launch_bounds__(256) void k_offsets(const int* __restrict__ deg, int* __restrict__ counter,
                                                 int* __restrict__ rowptr, int* __restrict__ cursor,
                                                 float* __restrict__ dis) {
  int n = blockIdx.x * 256 + threadIdx.x;
  int lane = threadIdx.x & 63;
  int d = (n < N_NODES) ? deg[n] : 0;
  // inclusive wave prefix sum of d
  int pre = d;
#pragma unroll
  for (int off = 1; off < 64; off <<= 1) {
    int v = __shfl_up(pre, off);
    if (lane >= off) pre += v;
  }
  int waveTotal = __shfl(pre, 63);
  int wbase = 0;
  if (lane == 63) wbase = atomicAdd(counter, waveTotal);
  wbase = __shfl(wbase, 63);
  if (n < N_NODES) {
    int off0 = wbase + pre - d;  // exclusive prefix within wave
    rowptr[n] = off0;
    cursor[n] = off0;
    dis[n] = d > 0 ? rsqrtf((float)d) : 0.0f;
  }
}

// ---------------- fill CSR (col + lap value), skipping self loops ------------
__global__ __launch_bounds__(256) void k_fill(const int* __restrict__ ei, const float* __restrict__ ew,
                                              const float* __restrict__ dis, int* __restrict__ cursor,
                                              int* __restrict__ ccol, float* __restrict__ cval) {
  int e = blockIdx.x * 256 + threadIdx.x;
  if (e >= N_EDGES) return;
  int r = ei[e];
  int c = ei[N_EDGES + e];
  if (r == c) return;
  float v = -dis[r] * ew[e] * dis[c];
  int pos = atomicAdd(&cursor[r], 1);
  ccol[pos] = c;
  cval[pos] = v;
}

// ---------------- SPMM: dst[b,n,:] = sum_e lap_e * src[b,col_e,:] ------------
// one wave64 per (b,n) row; lane = channel -> coalesced 256B gather per edge.
// 4-edge unroll: 4 outstanding gathers per wave (latency-bound on L2/L3 hits)
__global__ __launch_bounds__(256) void k_spmm(const float* __restrict__ src, float* __restrict__ dst,
                                              const int* __restrict__ rowptr, const int* __restrict__ deg,
                                              const int* __restrict__ ccol, const float* __restrict__ cval) {
  int wid = (blockIdx.x * 256 + threadIdx.x) >> 6;
  int lane = threadIdx.x & 63;
  if (wid >= BN_ROWS) return;
  int n = wid % N_NODES;
  int b = wid / N_NODES;
  const float* s = src + (size_t)b * N_NODES * N_C;
  int i = rowptr[n];
  int end = i + deg[n];
  float acc = 0.0f;
  for (; i + 3 < end; i += 4) {
    int c0 = ccol[i], c1 = ccol[i + 1], c2 = ccol[i + 2], c3 = ccol[i + 3];
    float v0 = cval[i], v1 = cval[i + 1], v2 = cval[i + 2], v3 = cval[i + 3];
    float x0 = s[(size_t)c0 * N_C + lane];
    float x1 = s[(size_t)c1 * N_C + lane];
    float x2 = s[(size_t)c2 * N_C + lane];
    float x3 = s[(size_t)c3 * N_C + lane];
    acc += v0 * x0;
    acc += v1 * x1;
    acc += v2 * x2;
    acc += v3 * x3;
  }
  for (; i < end; ++i) acc += cval[i] * s[(size_t)ccol[i] * N_C + lane];
  dst[(size_t)wid * N_C + lane] = acc;
}

// ---------------- fused GEMM: out = x@(W0-W2) + Tx1@W1 + Z@(2*W2) + bias -----
// Z is read from `out` itself (spmm2 wrote it there); each block reads only the
// rows it later writes, and all reads precede the stores -> safe in-place.
// Named accumulators + capped unroll => no scratch spill (round-2 lesson:
// full unroll + runtime-indexed pointer array spilled 2.8KB/thread = 1.1GB).
#define FMA4(ACC, AV, WV) \
  ACC.x += (AV) * (WV).x; ACC.y += (AV) * (WV).y; ACC.z += (AV) * (WV).z; ACC.w += (AV) * (WV).w;

#define CH_STEP(Wb, KK, A0, A1, A2, A3) { \
  const float4 wv0 = *(const float4*)&(Wb)[(k4 + (KK)) * 64 + tx8]; \
  const float4 wv1 = *(const float4*)&(Wb)[(k4 + (KK)) * 64 + tx8 + 4]; \
  FMA4(acc00, A0, wv0) FMA4(acc01, A0, wv1) \
  FMA4(acc10, A1, wv0) FMA4(acc11, A1, wv1) \
  FMA4(acc20, A2, wv0) FMA4(acc21, A2, wv1) \
  FMA4(acc30, A3, wv0) FMA4(acc31, A3, wv1) }

#define CH_PASS(Ab, Wb) \
  _Pragma("unroll 2") \
  for (int k4 = 0; k4 < 64; k4 += 4) { \
    const float4 a0 = *(const float4*)&(Ab)[r0 * 64 + (size_t)k4]; \
    const float4 a1 = *(const float4*)&(Ab)[r1 * 64 + (size_t)k4]; \
    const float4 a2 = *(const float4*)&(Ab)[r2 * 64 + (size_t)k4]; \
    const float4 a3 = *(const float4*)&(Ab)[r3 * 64 + (size_t)k4]; \
    CH_STEP(Wb, 0, a0.x, a1.x, a2.x, a3.x) \
    CH_STEP(Wb, 1, a0.y, a1.y, a2.y, a3.y) \
    CH_STEP(Wb, 2, a0.z, a1.z, a2.z, a3.z) \
    CH_STEP(Wb, 3, a0.w, a1.w, a2.w, a3.w) \
  }

__global__ __launch_bounds__(256) void k_gemm(const float* __restrict__ x,
                                              const float* __restrict__ tx1,
                                              const float* __restrict__ w,
                                              const float* __restrict__ bias,
                                              float* out) {
  __shared__ float wl[3 * 4096];  // 48KB combined weights -> 3 blocks/CU
  int t = threadIdx.x;
  for (int i = t; i < 4096; i += 256) {
    float w0 = w[i];
    float w1 = w[4096 + i];
    float w2 = w[8192 + i];
    wl[i] = w0 - w2;
    wl[4096 + i] = w1;
    wl[8192 + i] = 2.0f * w2;
  }
  __syncthreads();
  const int tx8 = (t & 7) * 8;        // cols tx8 .. tx8+7
  const int rg = t >> 3;              // 0..31 -> 4 rows each; tile = 128 rows
  const size_t base = (size_t)blockIdx.x * 128 + (size_t)rg * 4;
  const size_t rmax = BN_ROWS - 1;
  const size_t r0 = base + 0 < rmax ? base + 0 : rmax;
  const size_t r1 = base + 1 < rmax ? base + 1 : rmax;
  const size_t r2 = base + 2 < rmax ? base + 2 : rmax;
  const size_t r3 = base + 3 < rmax ? base + 3 : rmax;
  const float4 bv0 = *(const float4*)&bias[tx8];
  const float4 bv1 = *(const float4*)&bias[tx8 + 4];
  float4 acc00 = bv0, acc01 = bv1;
  float4 acc10 = bv0, acc11 = bv1;
  float4 acc20 = bv0, acc21 = bv1;
  float4 acc30 = bv0, acc31 = bv1;

  CH_PASS(x, wl)
  CH_PASS(tx1, (wl + 4096))
  CH_PASS(out, (wl + 8192))

  if (base + 0 < BN_ROWS) { *(float4*)&out[(base + 0) * 64 + tx8] = acc00; *(float4*)&out[(base + 0) * 64 + tx8 + 4] = acc01; }
  if (base + 1 < BN_ROWS) { *(float4*)&out[(base + 1) * 64 + tx8] = acc10; *(float4*)&out[(base + 1) * 64 + tx8 + 4] = acc11; }
  if (base + 2 < BN_ROWS) { *(float4*)&out[(base + 2) * 64 + tx8] = acc20; *(float4*)&out[(base + 2) * 64 + tx8 + 4] = acc21; }
  if (base + 3 < BN_ROWS) { *(float4*)&out[(base + 3) * 64 + tx8] = acc30; *(float4*)&out[(base + 3) * 64 + tx8 + 4] = acc31; }
}

extern "C" void kernel_launch(void* const* d_in, const int* in_sizes, int n_in,
                              void* d_out, int out_size, void* d_ws, size_t ws_size,
                              hipStream_t stream) {
  const float* x = (const float*)d_in[0];
  const int* ei = (const int*)d_in[1];        // [2, E] int32
  const float* ew = (const float*)d_in[2];
  const float* w = (const float*)d_in[3];     // [3,64,64]
  const float* bias = (const float*)d_in[4];  // [64]
  float* out = (float*)d_out;

  // workspace layout (4-byte units, 256B-aligned chunks)
  int* ws32 = (int*)d_ws;
  const size_t NA = 50048;  // padded N
  int* deg = ws32;                          // [0..N) degrees, [N] = global counter
  int* counter = deg + N_NODES;
  int* cursor = ws32 + NA;
  float* dis = (float*)(cursor + NA);
  int* rowptr = (int*)(dis + NA);
  int* ccol = rowptr + NA;
  float* cval = (float*)(ccol + N_EDGES);
  float* tx1 = cval + N_EDGES;             // BN_ROWS*64 floats
  const size_t NEED = ((size_t)(4 * NA + 2 * N_EDGES) + (size_t)BN_ROWS * N_C) * 4;
  if (ws_size < NEED) return;  // clean fail instead of corruption

  hipMemsetAsync(deg, 0, (N_NODES + 1) * sizeof(int), stream);  // deg + counter
  k_deg<<<(N_EDGES + 255) / 256, 256, 0, stream>>>(ei, deg);
  k_offsets<<<(N_NODES + 255) / 256, 256, 0, stream>>>(deg, counter, rowptr, cursor, dis);
  k_fill<<<(N_EDGES + 255) / 256, 256, 0, stream>>>(ei, ew, dis, cursor, ccol, cval);
  // Tx1 = L x
  k_spmm<<<(BN_ROWS * N_C) / 256, 256, 0, stream>>>(x, tx1, rowptr, deg, ccol, cval);
  // Z = L Tx1  (into d_out)
  k_spmm<<<(BN_ROWS * N_C) / 256, 256, 0, stream>>>(tx1, out, rowptr, deg, ccol, cval);
  // out = x@(W0-W2) + Tx1@W1 + Z@(2W2) + bias  (in-place over Z)
  k_gemm<<<(BN_ROWS + 127) / 128, 256, 0, stream>>>(x, tx1, w, bias, out);
}

// Round 5
// 355.728 us; speedup vs baseline: 3.5234x; 1.0408x over previous
//
#include <hip/hip_runtime.h>

#define N_NODES 50000
#define N_EDGES 800000
#define N_B 2
#define N_C 64
#define BN_ROWS (N_B * N_NODES)

__device__ inline unsigned short f2bf(float f) {
  unsigned int u = __float_as_uint(f);
  return (unsigned short)((u + 0x7fffu + ((u >> 16) & 1u)) >> 16);  // RNE
}
__device__ inline float bf2f(unsigned short h) { return __uint_as_float(((unsigned int)h) << 16); }

// ---------------- degree count (non-self-loop edges per source row) ----------
__global__ __launch_bounds__(256) void k_deg(const int* __restrict__ ei, int* __restrict__ deg) {
  int e = blockIdx.x * 256 + threadIdx.x;
  if (e >= N_EDGES) return;
  int r = ei[e];
  int c = ei[N_EDGES + e];
  if (r != c) atomicAdd(&deg[r], 1);
}

// ---------------- segment allocator: per-wave prefix + 1 atomic per wave -----
__global__ __launch_bounds__(256) void k_offsets(const int* __restrict__ deg, int* __restrict__ counter,
                                                 int* __restrict__ rowptr, int* __restrict__ cursor,
                                                 float* __restrict__ dis) {
  int n = blockIdx.x * 256 + threadIdx.x;
  int lane = threadIdx.x & 63;
  int d = (n < N_NODES) ? deg[n] : 0;
  int pre = d;
#pragma unroll
  for (int off = 1; off < 64; off <<= 1) {
    int v = __shfl_up(pre, off);
    if (lane >= off) pre += v;
  }
  int waveTotal = __shfl(pre, 63);
  int wbase = 0;
  if (lane == 63) wbase = atomicAdd(counter, waveTotal);
  wbase = __shfl(wbase, 63);
  if (n < N_NODES) {
    int off0 = wbase + pre - d;
    rowptr[n] = off0;
    cursor[n] = off0;
    dis[n] = d > 0 ? rsqrtf((float)d) : 0.0f;
  }
}

// ---------------- fill CSR: packed (col, lap) int2, one 8B scatter/edge ------
__global__ __launch_bounds__(256) void k_fill(const int* __restrict__ ei, const float* __restrict__ ew,
                                              const float* __restrict__ dis, int* __restrict__ cursor,
                                              int2* __restrict__ ccv) {
  int e = blockIdx.x * 256 + threadIdx.x;
  if (e >= N_EDGES) return;
  int r = ei[e];
  int c = ei[N_EDGES + e];
  if (r == c) return;
  float v = -dis[r] * ew[e] * dis[c];
  int pos = atomicAdd(&cursor[r], 1);
  ccv[pos] = make_int2(c, __float_as_int(v));
}

// ---------------- x (fp32) -> bf16 copy --------------------------------------
__global__ __launch_bounds__(256) void k_cvt(const float* __restrict__ x, unsigned short* __restrict__ xb) {
  int i = blockIdx.x * 256 + threadIdx.x;  // float4-quad index
  if (i >= BN_ROWS * 16) return;
  float4 v = ((const float4*)x)[i];
  ushort4 h;
  h.x = f2bf(v.x); h.y = f2bf(v.y); h.z = f2bf(v.z); h.w = f2bf(v.w);
  ((ushort4*)xb)[i] = h;
}

// ---------------- SPMM: dst[b,n,:] = sum_e lap_e * src[b,col_e,:] ------------
// one wave64 per (b,n) row; lane = channel; bf16 gather source (128B/edge)
template <int BFOUT>
__global__ __launch_bounds__(256) void k_spmm(const unsigned short* __restrict__ src, void* __restrict__ dstv,
                                              const int* __restrict__ rowptr, const int* __restrict__ deg,
                                              const int2* __restrict__ ccv) {
  int wid = (blockIdx.x * 256 + threadIdx.x) >> 6;
  int lane = threadIdx.x & 63;
  if (wid >= BN_ROWS) return;
  int n = wid % N_NODES;
  int b = wid / N_NODES;
  const unsigned short* s = src + (size_t)b * N_NODES * N_C;
  int i = rowptr[n];
  int end = i + deg[n];
  float acc = 0.0f;
  for (; i + 3 < end; i += 4) {
    int2 p0 = ccv[i], p1 = ccv[i + 1], p2 = ccv[i + 2], p3 = ccv[i + 3];
    float x0 = bf2f(s[(size_t)p0.x * N_C + lane]);
    float x1 = bf2f(s[(size_t)p1.x * N_C + lane]);
    float x2 = bf2f(s[(size_t)p2.x * N_C + lane]);
    float x3 = bf2f(s[(size_t)p3.x * N_C + lane]);
    acc += __int_as_float(p0.y) * x0;
    acc += __int_as_float(p1.y) * x1;
    acc += __int_as_float(p2.y) * x2;
    acc += __int_as_float(p3.y) * x3;
  }
  for (; i < end; ++i) {
    int2 p = ccv[i];
    acc += __int_as_float(p.y) * bf2f(s[(size_t)p.x * N_C + lane]);
  }
  if (BFOUT) {
    ((unsigned short*)dstv)[(size_t)wid * N_C + lane] = f2bf(acc);
  } else {
    ((float*)dstv)[(size_t)wid * N_C + lane] = acc;
  }
}

// ---------------- fused GEMM: out = x@(W0-W2) + Tx1@W1 + Z@(2*W2) + bias -----
// x, Tx1 read as bf16; Z read fp32 in-place from `out` (block-exclusive rows,
// all reads precede stores). Named accumulators + capped unroll (round-2
// lesson: full unroll + runtime-indexed pointer array spilled 1.1GB).
#define FMA4(ACC, AV, WV) \
  ACC.x += (AV) * (WV).x; ACC.y += (AV) * (WV).y; ACC.z += (AV) * (WV).z; ACC.w += (AV) * (WV).w;

#define CH_STEP(Wb, KK, A0, A1, A2, A3) { \
  const float4 wv0 = *(const float4*)&(Wb)[(k4 + (KK)) * 64 + tx8]; \
  const float4 wv1 = *(const float4*)&(Wb)[(k4 + (KK)) * 64 + tx8 + 4]; \
  FMA4(acc00, A0, wv0) FMA4(acc01, A0, wv1) \
  FMA4(acc10, A1, wv0) FMA4(acc11, A1, wv1) \
  FMA4(acc20, A2, wv0) FMA4(acc21, A2, wv1) \
  FMA4(acc30, A3, wv0) FMA4(acc31, A3, wv1) }

#define CH_BODY(A0, A1, A2, A3, Wb) \
    CH_STEP(Wb, 0, A0.x, A1.x, A2.x, A3.x) \
    CH_STEP(Wb, 1, A0.y, A1.y, A2.y, A3.y) \
    CH_STEP(Wb, 2, A0.z, A1.z, A2.z, A3.z) \
    CH_STEP(Wb, 3, A0.w, A1.w, A2.w, A3.w)

#define CH_PASS_F32(Ab, Wb) \
  _Pragma("unroll 2") \
  for (int k4 = 0; k4 < 64; k4 += 4) { \
    const float4 a0 = *(const float4*)&(Ab)[r0 * 64 + (size_t)k4]; \
    const float4 a1 = *(const float4*)&(Ab)[r1 * 64 + (size_t)k4]; \
    const float4 a2 = *(const float4*)&(Ab)[r2 * 64 + (size_t)k4]; \
    const float4 a3 = *(const float4*)&(Ab)[r3 * 64 + (size_t)k4]; \
    CH_BODY(a0, a1, a2, a3, Wb) \
  }

__device__ inline float4 u4f(ushort4 u) {
  return make_float4(bf2f(u.x), bf2f(u.y), bf2f(u.z), bf2f(u.w));
}

#define CH_PASS_BF(Ab, Wb) \
  _Pragma("unroll 2") \
  for (int k4 = 0; k4 < 64; k4 += 4) { \
    const float4 a0 = u4f(*(const ushort4*)&(Ab)[r0 * 64 + (size_t)k4]); \
    const float4 a1 = u4f(*(const ushort4*)&(Ab)[r1 * 64 + (size_t)k4]); \
    const float4 a2 = u4f(*(const ushort4*)&(Ab)[r2 * 64 + (size_t)k4]); \
    const float4 a3 = u4f(*(const ushort4*)&(Ab)[r3 * 64 + (size_t)k4]); \
    CH_BODY(a0, a1, a2, a3, Wb) \
  }

__global__ __launch_bounds__(256) void k_gemm(const unsigned short* __restrict__ xb,
                                              const unsigned short* __restrict__ t1h,
                                              const float* __restrict__ w,
                                              const float* __restrict__ bias,
                                              float* out) {
  __shared__ float wl[3 * 4096];  // 48KB combined weights
  int t = threadIdx.x;
  for (int i = t; i < 4096; i += 256) {
    float w0 = w[i];
    float w1 = w[4096 + i];
    float w2 = w[8192 + i];
    wl[i] = w0 - w2;
    wl[4096 + i] = w1;
    wl[8192 + i] = 2.0f * w2;
  }
  __syncthreads();
  const int tx8 = (t & 7) * 8;        // cols tx8 .. tx8+7
  const int rg = t >> 3;              // 0..31 -> 4 rows each; tile = 128 rows
  const size_t base = (size_t)blockIdx.x * 128 + (size_t)rg * 4;
  const size_t rmax = BN_ROWS - 1;
  const size_t r0 = base + 0 < rmax ? base + 0 : rmax;
  const size_t r1 = base + 1 < rmax ? base + 1 : rmax;
  const size_t r2 = base + 2 < rmax ? base + 2 : rmax;
  const size_t r3 = base + 3 < rmax ? base + 3 : rmax;
  const float4 bv0 = *(const float4*)&bias[tx8];
  const float4 bv1 = *(const float4*)&bias[tx8 + 4];
  float4 acc00 = bv0, acc01 = bv1;
  float4 acc10 = bv0, acc11 = bv1;
  float4 acc20 = bv0, acc21 = bv1;
  float4 acc30 = bv0, acc31 = bv1;

  CH_PASS_BF(xb, wl)
  CH_PASS_BF(t1h, (wl + 4096))
  CH_PASS_F32(out, (wl + 8192))

  if (base + 0 < BN_ROWS) { *(float4*)&out[(base + 0) * 64 + tx8] = acc00; *(float4*)&out[(base + 0) * 64 + tx8 + 4] = acc01; }
  if (base + 1 < BN_ROWS) { *(float4*)&out[(base + 1) * 64 + tx8] = acc10; *(float4*)&out[(base + 1) * 64 + tx8 + 4] = acc11; }
  if (base + 2 < BN_ROWS) { *(float4*)&out[(base + 2) * 64 + tx8] = acc20; *(float4*)&out[(base + 2) * 64 + tx8 + 4] = acc21; }
  if (base + 3 < BN_ROWS) { *(float4*)&out[(base + 3) * 64 + tx8] = acc30; *(float4*)&out[(base + 3) * 64 + tx8 + 4] = acc31; }
}

extern "C" void kernel_launch(void* const* d_in, const int* in_sizes, int n_in,
                              void* d_out, int out_size, void* d_ws, size_t ws_size,
                              hipStream_t stream) {
  const float* x = (const float*)d_in[0];
  const int* ei = (const int*)d_in[1];        // [2, E] int32
  const float* ew = (const float*)d_in[2];
  const float* w = (const float*)d_in[3];     // [3,64,64]
  const float* bias = (const float*)d_in[4];  // [64]
  float* out = (float*)d_out;

  // workspace layout (4-byte units)
  int* ws32 = (int*)d_ws;
  const size_t NA = 50048;  // padded N
  int* deg = ws32;                          // [0..N) degrees, [N] = counter
  int* counter = deg + N_NODES;
  int* cursor = ws32 + NA;
  float* dis = (float*)(cursor + NA);
  int* rowptr = (int*)(dis + NA);
  int2* ccv = (int2*)(rowptr + NA);                       // 2*E ints
  unsigned short* xb = (unsigned short*)(rowptr + NA + 2 * N_EDGES);   // BN_ROWS*64 bf16
  unsigned short* t1h = xb + (size_t)BN_ROWS * N_C;                    // BN_ROWS*64 bf16
  const size_t NEED = ((size_t)(4 * NA + 2 * N_EDGES) + (size_t)BN_ROWS * N_C) * 4;
  if (ws_size < NEED) return;  // clean fail instead of corruption

  hipMemsetAsync(deg, 0, (N_NODES + 1) * sizeof(int), stream);  // deg + counter
  k_cvt<<<(BN_ROWS * 16 + 255) / 256, 256, 0, stream>>>(x, xb);
  k_deg<<<(N_EDGES + 255) / 256, 256, 0, stream>>>(ei, deg);
  k_offsets<<<(N_NODES + 255) / 256, 256, 0, stream>>>(deg, counter, rowptr, cursor, dis);
  k_fill<<<(N_EDGES + 255) / 256, 256, 0, stream>>>(ei, ew, dis, cursor, ccv);
  // Tx1 = L x   (bf16 out)
  k_spmm<1><<<(BN_ROWS * N_C) / 256, 256, 0, stream>>>(xb, t1h, rowptr, deg, ccv);
  // Z = L Tx1   (fp32, into d_out)
  k_spmm<0><<<(BN_ROWS * N_C) / 256, 256, 0, stream>>>(t1h, out, rowptr, deg, ccv);
  // out = x@(W0-W2) + Tx1@W1 + Z@(2W2) + bias  (in-place over Z)
  k_gemm<<<(BN_ROWS + 127) / 128, 256, 0, stream>>>(xb, t1h, w, bias, out);
}

// Round 6
// 284.927 us; speedup vs baseline: 4.3989x; 1.2485x over previous
//
#include <hip/hip_runtime.h>

#define N_NODES 50000
#define N_EDGES 800000
#define N_B 2
#define N_C 64
#define BN_ROWS (N_B * N_NODES)

__device__ inline unsigned short f2bf(float f) {
  unsigned int u = __float_as_uint(f);
  return (unsigned short)((u + 0x7fffu + ((u >> 16) & 1u)) >> 16);  // RNE
}
__device__ inline float bf2f(unsigned short h) { return __uint_as_float(((unsigned int)h) << 16); }
__device__ inline float lof(unsigned int u) { return __uint_as_float(u << 16); }
__device__ inline float hif(unsigned int u) { return __uint_as_float(u & 0xffff0000u); }

// ---------------- degree count (non-self-loop edges per source row) ----------
__global__ __launch_bounds__(256) void k_deg(const int* __restrict__ ei, int* __restrict__ deg) {
  int e = blockIdx.x * 256 + threadIdx.x;
  if (e >= N_EDGES) return;
  int r = ei[e];
  int c = ei[N_EDGES + e];
  if (r != c) atomicAdd(&deg[r], 1);
}

// ---------------- segment allocator: per-wave prefix + 1 atomic per wave -----
__global__ __launch_bounds__(256) void k_offsets(const int* __restrict__ deg, int* __restrict__ counter,
                                                 int* __restrict__ rowptr, int* __restrict__ cursor,
                                                 float* __restrict__ dis) {
  int n = blockIdx.x * 256 + threadIdx.x;
  int lane = threadIdx.x & 63;
  int d = (n < N_NODES) ? deg[n] : 0;
  int pre = d;
#pragma unroll
  for (int off = 1; off < 64; off <<= 1) {
    int v = __shfl_up(pre, off);
    if (lane >= off) pre += v;
  }
  int waveTotal = __shfl(pre, 63);
  int wbase = 0;
  if (lane == 63) wbase = atomicAdd(counter, waveTotal);
  wbase = __shfl(wbase, 63);
  if (n < N_NODES) {
    int off0 = wbase + pre - d;
    rowptr[n] = off0;
    cursor[n] = off0;
    dis[n] = d > 0 ? rsqrtf((float)d) : 0.0f;
  }
}

// ---------------- fill CSR: packed (col, lap) int2, one 8B scatter/edge ------
__global__ __launch_bounds__(256) void k_fill(const int* __restrict__ ei, const float* __restrict__ ew,
                                              const float* __restrict__ dis, int* __restrict__ cursor,
                                              int2* __restrict__ ccv) {
  int e = blockIdx.x * 256 + threadIdx.x;
  if (e >= N_EDGES) return;
  int r = ei[e];
  int c = ei[N_EDGES + e];
  if (r == c) return;
  float v = -dis[r] * ew[e] * dis[c];
  int pos = atomicAdd(&cursor[r], 1);
  ccv[pos] = make_int2(c, __float_as_int(v));
}

// ---------------- x (fp32) -> bf16 copy --------------------------------------
__global__ __launch_bounds__(256) void k_cvt(const float* __restrict__ x, unsigned short* __restrict__ xb) {
  int i = blockIdx.x * 256 + threadIdx.x;  // float4-quad index
  if (i >= BN_ROWS * 16) return;
  float4 v = ((const float4*)x)[i];
  ushort4 h;
  h.x = f2bf(v.x); h.y = f2bf(v.y); h.z = f2bf(v.z); h.w = f2bf(v.w);
  ((ushort4*)xb)[i] = h;
}

// ---------------- SPMM: dst[b,n,:] = sum_e lap_e * src[b,col_e,:] ------------
// One wave per NODE, BOTH batches. lane = (edge-slot g = l>>3) x (channel
// group cg = l&7). Per 8 edges: 1 per-lane ccv load + 2 uint4 gathers (16B =
// 8 bf16 channels) -> 8x fewer load instructions than scalar-gather version
// (round-5: byte-halving left dur flat => instruction/latency-bound).
// Tail predicated (clamped idx, zeroed val). Epilogue: shfl_xor butterfly
// (8/16/32) then lanes g==0 / g==1 store batch0 / batch1 rows coalesced.
#define UNPK_FMA(Q, A0, A1, A2, A3, A4, A5, A6, A7, V) \
  A0 += (V) * lof(Q.x); A1 += (V) * hif(Q.x); \
  A2 += (V) * lof(Q.y); A3 += (V) * hif(Q.y); \
  A4 += (V) * lof(Q.z); A5 += (V) * hif(Q.z); \
  A6 += (V) * lof(Q.w); A7 += (V) * hif(Q.w);

#define RED3(A) { A += __shfl_xor(A, 8); A += __shfl_xor(A, 16); A += __shfl_xor(A, 32); }

template <int BFOUT>
__global__ __launch_bounds__(256) void k_spmm(const unsigned short* __restrict__ src, void* __restrict__ dstv,
                                              const int* __restrict__ rowptr, const int* __restrict__ deg,
                                              const int2* __restrict__ ccv) {
  int n = (blockIdx.x * 256 + threadIdx.x) >> 6;
  int lane = threadIdx.x & 63;
  if (n >= N_NODES) return;
  const int g = lane >> 3;
  const int cg = lane & 7;
  const unsigned short* s0 = src;
  const unsigned short* s1 = src + (size_t)N_NODES * N_C;
  int r0 = rowptr[n];
  int end = r0 + deg[n];
  float a00 = 0, a01 = 0, a02 = 0, a03 = 0, a04 = 0, a05 = 0, a06 = 0, a07 = 0;
  float a10 = 0, a11 = 0, a12 = 0, a13 = 0, a14 = 0, a15 = 0, a16 = 0, a17 = 0;
#pragma unroll 2
  for (int i = r0; i < end; i += 8) {
    int idx = i + g;
    bool ok = idx < end;
    int2 pe = ccv[ok ? idx : (end - 1)];
    float val = ok ? __int_as_float(pe.y) : 0.0f;
    size_t off = (size_t)pe.x * N_C + cg * 8;  // ushort units; 16B aligned
    uint4 q0 = *(const uint4*)(s0 + off);
    uint4 q1 = *(const uint4*)(s1 + off);
    UNPK_FMA(q0, a00, a01, a02, a03, a04, a05, a06, a07, val)
    UNPK_FMA(q1, a10, a11, a12, a13, a14, a15, a16, a17, val)
  }
  RED3(a00) RED3(a01) RED3(a02) RED3(a03) RED3(a04) RED3(a05) RED3(a06) RED3(a07)
  RED3(a10) RED3(a11) RED3(a12) RED3(a13) RED3(a14) RED3(a15) RED3(a16) RED3(a17)
  if (BFOUT) {
    unsigned short* d = (unsigned short*)dstv;
    if (g == 0) {
      uint4 o;
      o.x = (unsigned)f2bf(a00) | ((unsigned)f2bf(a01) << 16);
      o.y = (unsigned)f2bf(a02) | ((unsigned)f2bf(a03) << 16);
      o.z = (unsigned)f2bf(a04) | ((unsigned)f2bf(a05) << 16);
      o.w = (unsigned)f2bf(a06) | ((unsigned)f2bf(a07) << 16);
      *(uint4*)(d + (size_t)n * N_C + cg * 8) = o;
    } else if (g == 1) {
      uint4 o;
      o.x = (unsigned)f2bf(a10) | ((unsigned)f2bf(a11) << 16);
      o.y = (unsigned)f2bf(a12) | ((unsigned)f2bf(a13) << 16);
      o.z = (unsigned)f2bf(a14) | ((unsigned)f2bf(a15) << 16);
      o.w = (unsigned)f2bf(a16) | ((unsigned)f2bf(a17) << 16);
      *(uint4*)(d + ((size_t)N_NODES + n) * N_C + cg * 8) = o;
    }
  } else {
    float* d = (float*)dstv;
    if (g == 0) {
      *(float4*)(d + (size_t)n * N_C + cg * 8) = make_float4(a00, a01, a02, a03);
      *(float4*)(d + (size_t)n * N_C + cg * 8 + 4) = make_float4(a04, a05, a06, a07);
    } else if (g == 1) {
      *(float4*)(d + ((size_t)N_NODES + n) * N_C + cg * 8) = make_float4(a10, a11, a12, a13);
      *(float4*)(d + ((size_t)N_NODES + n) * N_C + cg * 8 + 4) = make_float4(a14, a15, a16, a17);
    }
  }
}

// ---------------- fused GEMM: out = x@(W0-W2) + Tx1@W1 + Z@(2*W2) + bias -----
// x, Tx1 read as bf16; Z read fp32 in-place from `out` (block-exclusive rows,
// all reads precede stores). Named accumulators + capped unroll (round-2
// lesson: full unroll + runtime-indexed pointer array spilled 1.1GB).
#define FMA4(ACC, AV, WV) \
  ACC.x += (AV) * (WV).x; ACC.y += (AV) * (WV).y; ACC.z += (AV) * (WV).z; ACC.w += (AV) * (WV).w;

#define CH_STEP(Wb, KK, A0, A1, A2, A3) { \
  const float4 wv0 = *(const float4*)&(Wb)[(k4 + (KK)) * 64 + tx8]; \
  const float4 wv1 = *(const float4*)&(Wb)[(k4 + (KK)) * 64 + tx8 + 4]; \
  FMA4(acc00, A0, wv0) FMA4(acc01, A0, wv1) \
  FMA4(acc10, A1, wv0) FMA4(acc11, A1, wv1) \
  FMA4(acc20, A2, wv0) FMA4(acc21, A2, wv1) \
  FMA4(acc30, A3, wv0) FMA4(acc31, A3, wv1) }

#define CH_BODY(A0, A1, A2, A3, Wb) \
    CH_STEP(Wb, 0, A0.x, A1.x, A2.x, A3.x) \
    CH_STEP(Wb, 1, A0.y, A1.y, A2.y, A3.y) \
    CH_STEP(Wb, 2, A0.z, A1.z, A2.z, A3.z) \
    CH_STEP(Wb, 3, A0.w, A1.w, A2.w, A3.w)

#define CH_PASS_F32(Ab, Wb) \
  _Pragma("unroll 2") \
  for (int k4 = 0; k4 < 64; k4 += 4) { \
    const float4 a0 = *(const float4*)&(Ab)[r0 * 64 + (size_t)k4]; \
    const float4 a1 = *(const float4*)&(Ab)[r1 * 64 + (size_t)k4]; \
    const float4 a2 = *(const float4*)&(Ab)[r2 * 64 + (size_t)k4]; \
    const float4 a3 = *(const float4*)&(Ab)[r3 * 64 + (size_t)k4]; \
    CH_BODY(a0, a1, a2, a3, Wb) \
  }

__device__ inline float4 u4f(ushort4 u) {
  return make_float4(bf2f(u.x), bf2f(u.y), bf2f(u.z), bf2f(u.w));
}

#define CH_PASS_BF(Ab, Wb) \
  _Pragma("unroll 2") \
  for (int k4 = 0; k4 < 64; k4 += 4) { \
    const float4 a0 = u4f(*(const ushort4*)&(Ab)[r0 * 64 + (size_t)k4]); \
    const float4 a1 = u4f(*(const ushort4*)&(Ab)[r1 * 64 + (size_t)k4]); \
    const float4 a2 = u4f(*(const ushort4*)&(Ab)[r2 * 64 + (size_t)k4]); \
    const float4 a3 = u4f(*(const ushort4*)&(Ab)[r3 * 64 + (size_t)k4]); \
    CH_BODY(a0, a1, a2, a3, Wb) \
  }

__global__ __launch_bounds__(256) void k_gemm(const unsigned short* __restrict__ xb,
                                              const unsigned short* __restrict__ t1h,
                                              const float* __restrict__ w,
                                              const float* __restrict__ bias,
                                              float* out) {
  __shared__ float wl[3 * 4096];  // 48KB combined weights
  int t = threadIdx.x;
  for (int i = t; i < 4096; i += 256) {
    float w0 = w[i];
    float w1 = w[4096 + i];
    float w2 = w[8192 + i];
    wl[i] = w0 - w2;
    wl[4096 + i] = w1;
    wl[8192 + i] = 2.0f * w2;
  }
  __syncthreads();
  const int tx8 = (t & 7) * 8;        // cols tx8 .. tx8+7
  const int rg = t >> 3;              // 0..31 -> 4 rows each; tile = 128 rows
  const size_t base = (size_t)blockIdx.x * 128 + (size_t)rg * 4;
  const size_t rmax = BN_ROWS - 1;
  const size_t r0 = base + 0 < rmax ? base + 0 : rmax;
  const size_t r1 = base + 1 < rmax ? base + 1 : rmax;
  const size_t r2 = base + 2 < rmax ? base + 2 : rmax;
  const size_t r3 = base + 3 < rmax ? base + 3 : rmax;
  const float4 bv0 = *(const float4*)&bias[tx8];
  const float4 bv1 = *(const float4*)&bias[tx8 + 4];
  float4 acc00 = bv0, acc01 = bv1;
  float4 acc10 = bv0, acc11 = bv1;
  float4 acc20 = bv0, acc21 = bv1;
  float4 acc30 = bv0, acc31 = bv1;

  CH_PASS_BF(xb, wl)
  CH_PASS_BF(t1h, (wl + 4096))
  CH_PASS_F32(out, (wl + 8192))

  if (base + 0 < BN_ROWS) { *(float4*)&out[(base + 0) * 64 + tx8] = acc00; *(float4*)&out[(base + 0) * 64 + tx8 + 4] = acc01; }
  if (base + 1 < BN_ROWS) { *(float4*)&out[(base + 1) * 64 + tx8] = acc10; *(float4*)&out[(base + 1) * 64 + tx8 + 4] = acc11; }
  if (base + 2 < BN_ROWS) { *(float4*)&out[(base + 2) * 64 + tx8] = acc20; *(float4*)&out[(base + 2) * 64 + tx8 + 4] = acc21; }
  if (base + 3 < BN_ROWS) { *(float4*)&out[(base + 3) * 64 + tx8] = acc30; *(float4*)&out[(base + 3) * 64 + tx8 + 4] = acc31; }
}

extern "C" void kernel_launch(void* const* d_in, const int* in_sizes, int n_in,
                              void* d_out, int out_size, void* d_ws, size_t ws_size,
                              hipStream_t stream) {
  const float* x = (const float*)d_in[0];
  const int* ei = (const int*)d_in[1];        // [2, E] int32
  const float* ew = (const float*)d_in[2];
  const float* w = (const float*)d_in[3];     // [3,64,64]
  const float* bias = (const float*)d_in[4];  // [64]
  float* out = (float*)d_out;

  // workspace layout (4-byte units)
  int* ws32 = (int*)d_ws;
  const size_t NA = 50048;  // padded N (divisible by 16 -> keeps 16B alignment)
  int* deg = ws32;                          // [0..N) degrees, [N] = counter
  int* counter = deg + N_NODES;
  int* cursor = ws32 + NA;
  float* dis = (float*)(cursor + NA);
  int* rowptr = (int*)(dis + NA);
  int2* ccv = (int2*)(rowptr + NA);                       // 2*E ints
  unsigned short* xb = (unsigned short*)(rowptr + NA + 2 * N_EDGES);   // BN_ROWS*64 bf16
  unsigned short* t1h = xb + (size_t)BN_ROWS * N_C;                    // BN_ROWS*64 bf16
  const size_t NEED = ((size_t)(4 * NA + 2 * N_EDGES) + (size_t)BN_ROWS * N_C) * 4;
  if (ws_size < NEED) return;  // clean fail instead of corruption

  hipMemsetAsync(deg, 0, (N_NODES + 1) * sizeof(int), stream);  // deg + counter
  k_cvt<<<(BN_ROWS * 16 + 255) / 256, 256, 0, stream>>>(x, xb);
  k_deg<<<(N_EDGES + 255) / 256, 256, 0, stream>>>(ei, deg);
  k_offsets<<<(N_NODES + 255) / 256, 256, 0, stream>>>(deg, counter, rowptr, cursor, dis);
  k_fill<<<(N_EDGES + 255) / 256, 256, 0, stream>>>(ei, ew, dis, cursor, ccv);
  // Tx1 = L x   (bf16 out, both batches per wave)
  k_spmm<1><<<(N_NODES * 64 + 255) / 256, 256, 0, stream>>>(xb, t1h, rowptr, deg, ccv);
  // Z = L Tx1   (fp32, into d_out, both batches per wave)
  k_spmm<0><<<(N_NODES * 64 + 255) / 256, 256, 0, stream>>>(t1h, out, rowptr, deg, ccv);
  // out = x@(W0-W2) + Tx1@W1 + Z@(2W2) + bias  (in-place over Z)
  k_gemm<<<(BN_ROWS + 127) / 128, 256, 0, stream>>>(xb, t1h, w, bias, out);
}